// Round 2
// 208.734 us; speedup vs baseline: 1.0417x; 1.0417x over previous
//
#include <hip/hip_runtime.h>
#include <hip/hip_bf16.h>
#include <cstdint>
#include <cstddef>

#define N_TOK 65536
#define DIM 128
#define HID 256
#define NE 32
#define TOPK 2

typedef __bf16 bf16x8 __attribute__((ext_vector_type(8)));
typedef float f32x4 __attribute__((ext_vector_type(4)));
typedef unsigned uint4v __attribute__((ext_vector_type(4)));

__device__ __forceinline__ unsigned short f2bf(float f) {
  unsigned u = __builtin_bit_cast(unsigned, f);
  u += 0x7fffu + ((u >> 16) & 1u);   // round-to-nearest-even
  return (unsigned short)(u >> 16);
}
__device__ __forceinline__ float bf2f(unsigned s) {
  return __builtin_bit_cast(float, s << 16);
}
// truncation split: f = hi + lo + O(2^-14 |f|); packs two values' shorts into one uint.
__device__ __forceinline__ uint2 split2(float f0, float f1) {
  unsigned u0 = __builtin_bit_cast(unsigned, f0);
  unsigned u1 = __builtin_bit_cast(unsigned, f1);
  unsigned hi = (u0 >> 16) | (u1 & 0xffff0000u);
  float r0 = f0 - __builtin_bit_cast(float, u0 & 0xffff0000u);
  float r1 = f1 - __builtin_bit_cast(float, u1 & 0xffff0000u);
  unsigned lo = (__builtin_bit_cast(unsigned, r0) >> 16) |
                (__builtin_bit_cast(unsigned, r1) & 0xffff0000u);
  uint2 ret; ret.x = hi; ret.y = lo;
  return ret;
}

// ---------------- fallback-only: zero out ----------------
__global__ void k_zero_out(float* __restrict__ out) {
  int t = blockIdx.x * 256 + threadIdx.x;
  float4 z = make_float4(0.f, 0.f, 0.f, 0.f);
  float4* o4 = (float4*)out;
  o4[t] = z;
  o4[t + 1048576] = z;
}

// ---------------- convert + transpose weights (K-chunk-tiled) + router weight prep ----------------
// w1t[e]: element (h,d) at (d>>5)*8192 + h*32 + (d&31)
// w2t[e]: element (d,h) at (h>>5)*4096 + d*32 + (h&31)
// wrt64: fp64 Wr^T column-major [e][d]
// wrb: bf16 hi/lo B-fragments of Wr for mfma_16x16x32: [s][nt][kc][q][n][j], 16384 shorts
__global__ void k_weights(const float* __restrict__ W1, const float* __restrict__ W2,
                          const float* __restrict__ Wr,
                          unsigned short* __restrict__ w1t, unsigned short* __restrict__ w2t,
                          double* __restrict__ wrt64, unsigned short* __restrict__ wrb,
                          float* __restrict__ ws32, int* __restrict__ n_suspect) {
  int b = blockIdx.x;
  if (b == 512) {
    if (threadIdx.x == 0) *n_suspect = 0;
#pragma unroll
    for (int j = 0; j < 16; ++j) {    // fp64 Wr^T
      int idx = j * 256 + threadIdx.x;
      int e = idx >> 7, d = idx & 127;
      wrt64[idx] = (double)Wr[d * NE + e];
    }
#pragma unroll
    for (int j = 0; j < 16; ++j) {    // bf16 hi/lo B-fragments
      int idx = j * 256 + threadIdx.x;
      int k = idx >> 5, e = idx & 31;
      float w = Wr[k * NE + e];
      unsigned u = __builtin_bit_cast(unsigned, w);
      unsigned short hs = (unsigned short)(u >> 16);
      float r = w - __builtin_bit_cast(float, u & 0xffff0000u);
      unsigned short ls = (unsigned short)(__builtin_bit_cast(unsigned, r) >> 16);
      int nt = e >> 4, n = e & 15, kc = k >> 5, q = (k >> 3) & 3, jj = k & 7;
      size_t base = ((((size_t)nt * 4 + kc) * 4 + q) * 16 + n) * 8 + jj;
      wrb[base] = hs;
      wrb[8192 + base] = ls;
    }
    return;
  }
  if (b == 0 && threadIdx.x < 96) ws32[threadIdx.x] = 0.f;
  const float* in;
  unsigned short* out;
  int K, r0, c0;
  if (b < 256) {
    int e = b >> 3, tt = b & 7;
    in = W1 + (size_t)e * DIM * HID;   // [d][h] 128x256
    out = w1t + (size_t)e * DIM * HID;
    K = HID;
    r0 = (tt >> 2) * 64; c0 = (tt & 3) * 64;
  } else {
    b -= 256;
    int e = b >> 3, tt = b & 7;
    in = W2 + (size_t)e * HID * DIM;   // [h][d] 256x128
    out = w2t + (size_t)e * HID * DIM;
    K = DIM;
    r0 = (tt >> 1) * 64; c0 = (tt & 1) * 64;
  }
  __shared__ float tile[64][65];
  int t2 = threadIdx.x;
  int r = t2 >> 2, cs = (t2 & 3) * 16;
  const float* src = in + (size_t)(r0 + r) * K + c0 + cs;
#pragma unroll
  for (int j = 0; j < 4; ++j) {
    float4 v = *(const float4*)(src + j * 4);
    tile[r][cs + j * 4 + 0] = v.x;
    tile[r][cs + j * 4 + 1] = v.y;
    tile[r][cs + j * 4 + 2] = v.z;
    tile[r][cs + j * 4 + 3] = v.w;
  }
  __syncthreads();
#pragma unroll
  for (int p = 0; p < 2; ++p) {
    int orow = p * 32 + (t2 >> 3);
    int oc8 = (t2 & 7) * 8;
    int rr = r0 + oc8;
    unsigned pk[4];
#pragma unroll
    for (int q = 0; q < 4; ++q) {
      unsigned lo = f2bf(tile[oc8 + 2 * q][orow]);
      unsigned hi = f2bf(tile[oc8 + 2 * q + 1][orow]);
      pk[q] = lo | (hi << 16);
    }
    uint4 u;
    u.x = pk[0]; u.y = pk[1]; u.z = pk[2]; u.w = pk[3];
    size_t addr = (size_t)(rr >> 5) * (K * 32) + (size_t)(c0 + orow) * 32 + (rr & 31);
    *(uint4*)(out + addr) = u;
  }
}

// ---------------- router: MFMA split-precision logits + in-register top-2 ----------------
// Also: emits xb = bf16(x) (row-major, for k_expert's gather) and fused histogram.
// Grid 512, 128 tokens/block (2 blocks/CU for latency hiding).
__global__ __launch_bounds__(256, 2) void k_router(
    const float* __restrict__ x, const unsigned short* __restrict__ wrb,
    const float* __restrict__ br, int* __restrict__ top_idx, float* __restrict__ top_val,
    unsigned short* __restrict__ xb, int* __restrict__ counts,
    float* __restrict__ importance, int* __restrict__ suspects,
    int* __restrict__ n_suspect) {
  __shared__ int hc[NE];
  __shared__ float hf[NE];
  int t = threadIdx.x;
  if (t < NE) { hc[t] = 0; hf[t] = 0.f; }
  __syncthreads();
  int w = t >> 6, l = t & 63, quad = l >> 4, l15 = l & 15;
  int tok0 = blockIdx.x * 128 + w * 32;

  // B fragments (L1-hot, 32 KB total): [s hi/lo][nt][kc]
  bf16x8 bfr[2][2][4];
#pragma unroll
  for (int s = 0; s < 2; ++s)
#pragma unroll
    for (int nt = 0; nt < 2; ++nt)
#pragma unroll
      for (int kc = 0; kc < 4; ++kc)
        bfr[s][nt][kc] = *(const bf16x8*)(wrb + s * 8192 +
                          ((((size_t)nt * 4 + kc) * 4 + quad) * 16 + l15) * 8);

  f32x4 acc[2][2];
#pragma unroll
  for (int a = 0; a < 2; ++a)
#pragma unroll
    for (int b = 0; b < 2; ++b) {
      f32x4 z = {0.f, 0.f, 0.f, 0.f};
      acc[a][b] = z;
    }

#pragma unroll
  for (int mt = 0; mt < 2; ++mt) {
    const float* xp = x + (size_t)(tok0 + mt * 16 + l15) * DIM + quad * 8;
    float4 va[4][2];
#pragma unroll
    for (int kc = 0; kc < 4; ++kc) {
      const float4* p = (const float4*)(xp + kc * 32);
      va[kc][0] = p[0];
      va[kc][1] = p[1];
    }
    // bf16 row-major copy of x for k_expert's gather (identical RNE as before)
    unsigned short* xrow = xb + (size_t)(tok0 + mt * 16 + l15) * DIM + quad * 8;
#pragma unroll
    for (int kc = 0; kc < 4; ++kc) {
      uint4 u;
      u.x = (unsigned)f2bf(va[kc][0].x) | ((unsigned)f2bf(va[kc][0].y) << 16);
      u.y = (unsigned)f2bf(va[kc][0].z) | ((unsigned)f2bf(va[kc][0].w) << 16);
      u.z = (unsigned)f2bf(va[kc][1].x) | ((unsigned)f2bf(va[kc][1].y) << 16);
      u.w = (unsigned)f2bf(va[kc][1].z) | ((unsigned)f2bf(va[kc][1].w) << 16);
      *(uint4*)(xrow + kc * 32) = u;
    }
#pragma unroll
    for (int kc = 0; kc < 4; ++kc) {
      uint2 s0 = split2(va[kc][0].x, va[kc][0].y);
      uint2 s1 = split2(va[kc][0].z, va[kc][0].w);
      uint2 s2 = split2(va[kc][1].x, va[kc][1].y);
      uint2 s3 = split2(va[kc][1].z, va[kc][1].w);
      uint4v hu, lu;
      hu[0] = s0.x; lu[0] = s0.y;
      hu[1] = s1.x; lu[1] = s1.y;
      hu[2] = s2.x; lu[2] = s2.y;
      hu[3] = s3.x; lu[3] = s3.y;
      bf16x8 ahi = __builtin_bit_cast(bf16x8, hu);
      bf16x8 alo = __builtin_bit_cast(bf16x8, lu);
#pragma unroll
      for (int nt = 0; nt < 2; ++nt) {
        acc[mt][nt] = __builtin_amdgcn_mfma_f32_16x16x32_bf16(ahi, bfr[0][nt][kc], acc[mt][nt], 0, 0, 0);
        acc[mt][nt] = __builtin_amdgcn_mfma_f32_16x16x32_bf16(ahi, bfr[1][nt][kc], acc[mt][nt], 0, 0, 0);
        acc[mt][nt] = __builtin_amdgcn_mfma_f32_16x16x32_bf16(alo, bfr[0][nt][kc], acc[mt][nt], 0, 0, 0);
      }
    }
  }

  float brv0 = br[l15], brv1 = br[16 + l15];
  const float NINF = -3.0e38f;
#pragma unroll
  for (int mt = 0; mt < 2; ++mt) {
#pragma unroll
    for (int r = 0; r < 4; ++r) {
      float c0 = acc[mt][0][r] + brv0;
      float c1 = acc[mt][1][r] + brv1;
      // pass 1: max with lowest-index tiebreak
      float va = (c0 >= c1) ? c0 : c1;
      int ia = (c0 >= c1) ? l15 : 16 + l15;
#pragma unroll
      for (int off = 1; off < 16; off <<= 1) {
        float ov = __shfl_xor(va, off);
        int oi = __shfl_xor(ia, off);
        if (ov > va || (ov == va && oi < ia)) { va = ov; ia = oi; }
      }
      float v1 = va; int i1 = ia;
      // pass 2
      float d0 = (i1 == l15) ? NINF : c0;
      float d1 = (i1 == 16 + l15) ? NINF : c1;
      float vb = (d0 >= d1) ? d0 : d1;
      int ib = (d0 >= d1) ? l15 : 16 + l15;
#pragma unroll
      for (int off = 1; off < 16; off <<= 1) {
        float ov = __shfl_xor(vb, off);
        int oi = __shfl_xor(ib, off);
        if (ov > vb || (ov == vb && oi < ib)) { vb = ov; ib = oi; }
      }
      float v2 = vb; int i2 = ib;
      // pass 3: third-largest value (for suspect detection)
      float e0 = (i1 == l15 || i2 == l15) ? NINF : c0;
      float e1 = (i1 == 16 + l15 || i2 == 16 + l15) ? NINF : c1;
      float vc = (e0 >= e1) ? e0 : e1;
#pragma unroll
      for (int off = 1; off < 16; off <<= 1) {
        float ov = __shfl_xor(vc, off);
        vc = (ov > vc) ? ov : vc;
      }
      // softmax denominator
      float s = __expf(c0 - v1) + __expf(c1 - v1);
#pragma unroll
      for (int off = 1; off < 16; off <<= 1) s += __shfl_xor(s, off);
      if (l15 == 0) {
        int n = tok0 + mt * 16 + quad * 4 + r;
        int2 ti; ti.x = i1; ti.y = i2;
        float2 tv; tv.x = 1.0f / s; tv.y = __expf(v2 - v1) / s;
        ((int2*)top_idx)[n] = ti;
        ((float2*)top_val)[n] = tv;
        atomicAdd(&hc[i1], 1);
        atomicAdd(&hc[i2], 1);
        atomicAdd(&hf[i1], tv.x);
        atomicAdd(&hf[i2], tv.y);
        if (v2 - vc < 2e-3f) {
          int sidx = atomicAdd(n_suspect, 1);
          if (sidx < 65536) suspects[sidx] = n;
        }
      }
    }
  }
  __syncthreads();
  if (t < NE) {
    atomicAdd(&counts[t], hc[t]);
    atomicAdd(&importance[t], hf[t]);
  }
}

// ---------------- fp64 re-resolution of near-tie tokens (+ hist delta patch) ----------------
__global__ __launch_bounds__(256) void k_router_fix(
    const float* __restrict__ x, const double* __restrict__ wrt64,
    const float* __restrict__ br, const int* __restrict__ suspects,
    const int* __restrict__ n_suspect, int* __restrict__ top_idx,
    float* __restrict__ top_val, int* __restrict__ counts,
    float* __restrict__ importance) {
  int t = threadIdx.x;
  int lt = t & 31;
  int gid = blockIdx.x * 8 + (t >> 5);
  int cnt = *n_suspect;
  if (cnt > 65536) cnt = 65536;
  const double* wcol = wrt64 + lt * DIM;
  for (int s = gid; s < cnt; s += 128 * 8) {
    int n = suspects[s];
    const float* xr = x + (size_t)n * DIM;
    double a = 0.0;
#pragma unroll 8
    for (int d = 0; d < DIM; ++d) a = fma((double)xr[d], wcol[d], a);
    double lv = a + (double)br[lt];

    double v1 = lv; int i1 = lt;
#pragma unroll
    for (int off = 16; off > 0; off >>= 1) {
      double ov = __shfl_xor(v1, off, 32);
      int oi = __shfl_xor(i1, off, 32);
      if (ov > v1 || (ov == v1 && oi < i1)) { v1 = ov; i1 = oi; }
    }
    double lv2 = (lt == i1) ? -1.0e300 : lv;
    double v2 = lv2; int i2 = lt;
#pragma unroll
    for (int off = 16; off > 0; off >>= 1) {
      double ov = __shfl_xor(v2, off, 32);
      int oi = __shfl_xor(i2, off, 32);
      if (ov > v2 || (ov == v2 && oi < i2)) { v2 = ov; i2 = oi; }
    }
    float p = expf((float)(lv - v1));
    float ssum = p;
#pragma unroll
    for (int off = 16; off > 0; off >>= 1) ssum += __shfl_xor(ssum, off, 32);
    if (lt == 0) {
      int o1 = top_idx[n * 2 + 0];
      int o2 = top_idx[n * 2 + 1];
      float w1v = top_val[n * 2 + 0];
      float w2v = top_val[n * 2 + 1];
      float nv1 = 1.0f / ssum;
      float nv2 = expf((float)(v2 - v1)) / ssum;
      // patch the fused histogram (router counted pre-fix values)
      if (o1 != i1) { atomicAdd(&counts[o1], -1); atomicAdd(&counts[i1], 1); }
      if (o2 != i2) { atomicAdd(&counts[o2], -1); atomicAdd(&counts[i2], 1); }
      atomicAdd(&importance[o1], -w1v);
      atomicAdd(&importance[o2], -w2v);
      atomicAdd(&importance[i1], nv1);
      atomicAdd(&importance[i2], nv2);
      top_idx[n * 2 + 0] = i1;
      top_idx[n * 2 + 1] = i2;
      top_val[n * 2 + 0] = nv1;
      top_val[n * 2 + 1] = nv2;
    }
  }
}

// ---------------- fallback-only: fp64 router ----------------
__global__ __launch_bounds__(256) void k_router_f64(const float* __restrict__ x,
                                                    const double* __restrict__ wrt64,
                                                    const float* __restrict__ br,
                                                    int* __restrict__ top_idx,
                                                    float* __restrict__ top_val) {
  int t = threadIdx.x;
  int lt = t & 31;
  int n = blockIdx.x * 8 + (t >> 5);
  const double* wcol = wrt64 + lt * DIM;
  const float* xr = x + (size_t)n * DIM;
  double a = 0.0;
#pragma unroll 8
  for (int d = 0; d < DIM; ++d) a = fma((double)xr[d], wcol[d], a);
  double lv = a + (double)br[lt];
  double v1 = lv; int i1 = lt;
#pragma unroll
  for (int off = 16; off > 0; off >>= 1) {
    double ov = __shfl_xor(v1, off, 32);
    int oi = __shfl_xor(i1, off, 32);
    if (ov > v1 || (ov == v1 && oi < i1)) { v1 = ov; i1 = oi; }
  }
  double lv2 = (lt == i1) ? -1.0e300 : lv;
  double v2 = lv2; int i2 = lt;
#pragma unroll
  for (int off = 16; off > 0; off >>= 1) {
    double ov = __shfl_xor(v2, off, 32);
    int oi = __shfl_xor(i2, off, 32);
    if (ov > v2 || (ov == v2 && oi < i2)) { v2 = ov; i2 = oi; }
  }
  float p = expf((float)(lv - v1));
  float ssum = p;
#pragma unroll
  for (int off = 16; off > 0; off >>= 1) ssum += __shfl_xor(ssum, off, 32);
  if (lt == 0) {
    top_idx[n * 2 + 0] = i1;
    top_idx[n * 2 + 1] = i2;
    top_val[n * 2 + 0] = 1.0f / ssum;
    top_val[n * 2 + 1] = expf((float)(v2 - v1)) / ssum;
  }
}

// ---------------- fallback-only: histogram (main path fuses this into k_router) ----------------
__global__ void k_hist(const int* __restrict__ top_idx, const float* __restrict__ top_val,
                       int* __restrict__ counts, float* __restrict__ importance) {
  __shared__ int hc[NE];
  __shared__ float hf[NE];
  int t = threadIdx.x;
  if (t < NE) { hc[t] = 0; hf[t] = 0.f; }
  __syncthreads();
#pragma unroll
  for (int j = 0; j < 2; ++j) {
    int i = (j * 256 + blockIdx.x) * 256 + t;
    int e = top_idx[i];
    atomicAdd(&hc[e], 1);
    atomicAdd(&hf[e], top_val[i]);
  }
  __syncthreads();
  if (t < NE) {
    atomicAdd(&counts[t], hc[t]);
    atomicAdd(&importance[t], hf[t]);
  }
}

// ---------------- scatter into per-expert lists (+ local scan, block0: offsets + loss) ----------------
__global__ void k_scatter(const int* __restrict__ top_idx, const float* __restrict__ top_val,
                          const int* __restrict__ counts, const float* __restrict__ importance,
                          int* __restrict__ cursors, int* __restrict__ perm,
                          float* __restrict__ gatev, int* __restrict__ inv,
                          int* __restrict__ offsets, float* __restrict__ out_loss) {
  __shared__ int hist[NE], base[NE], cur[NE], soff[NE];
  int t = threadIdx.x;
  if (t < NE) { hist[t] = 0; cur[t] = 0; }
  if (t < 32) {
    // every block recomputes the trivial 32-wide padded scan (cheaper than a kernel)
    int pc = (counts[t] + 63) & ~63;
    int sc = pc;
#pragma unroll
    for (int off = 1; off < 32; off <<= 1) {
      int ov = __shfl_up(sc, off, 32);
      if (t >= off) sc += ov;
    }
    soff[t] = sc - pc;
    if (blockIdx.x == 0) {
      offsets[t] = sc - pc;
      if (t == 31) offsets[NE] = sc;
      float imp = importance[t];
      float ssum = imp;
#pragma unroll
      for (int off = 16; off > 0; off >>= 1) ssum += __shfl_xor(ssum, off, 32);
      float mean = ssum / 32.0f;
      float dlt = imp - mean;
      float v = dlt * dlt;
#pragma unroll
      for (int off = 16; off > 0; off >>= 1) v += __shfl_xor(v, off, 32);
      if (t == 0) *out_loss = (v / 31.0f) / (mean * mean + 1e-9f);
    }
  }
  __syncthreads();
#pragma unroll
  for (int j = 0; j < 4; ++j) {
    int i = blockIdx.x * 1024 + j * 256 + t;
    atomicAdd(&hist[top_idx[i]], 1);
  }
  __syncthreads();
  if (t < NE) base[t] = atomicAdd(&cursors[t], hist[t]);
  __syncthreads();
#pragma unroll
  for (int j = 0; j < 4; ++j) {
    int i = blockIdx.x * 1024 + j * 256 + t;
    int e = top_idx[i];
    int p = atomicAdd(&cur[e], 1);
    int pos = soff[e] + base[e] + p;
    perm[pos] = i >> 1;
    gatev[pos] = top_val[i];
    inv[i] = pos;
  }
}

// ---------------- fused expert GEMM: 64 tokens x 1 expert per block ----------------
// YB=1: bf16 gather from xb, ybuf output. YB=0 (fallback): fp32 gather from x, atomic out.
template <int YB>
__global__ __launch_bounds__(256, 3) void k_expert(
    const float* __restrict__ x, const unsigned short* __restrict__ xb,
    const unsigned short* __restrict__ w1t, const unsigned short* __restrict__ w2t,
    const float* __restrict__ b1, const float* __restrict__ b2,
    const int* __restrict__ offsets, const int* __restrict__ counts,
    const int* __restrict__ perm, const float* __restrict__ gatev,
    unsigned short* __restrict__ ybuf, float* __restrict__ out) {
  __shared__ __align__(16) unsigned char smem[49152];
  unsigned char* xa = smem;                 // 16 KB: [c 0..15][row 0..63][16B]
  unsigned char* ha = smem + 16384;         // 32 KB: [c 0..31][row 0..63][16B]

  // XCD-affinity swizzle (2080 = 8*260, bijective): consecutive logical blocks
  // (same expert) land on the same XCD so each XCD L2 holds ~4 experts' weights.
  int bid = (int)(blockIdx.x & 7) * 260 + (int)(blockIdx.x >> 3);
  int slot0 = bid * 64;
  if (slot0 >= offsets[NE]) return;
  int e = 0;
#pragma unroll
  for (int i = 1; i < NE; ++i)
    if (slot0 >= offsets[i]) e = i;
  int cnt = counts[e];
  int local0 = slot0 - offsets[e];
  int nvalid = min(64, cnt - local0);

  int t = threadIdx.x;
  int w = t >> 6;
  int l = t & 63;
  int quad = l >> 4;
  int l15 = l & 15;

  if (YB) {
    // gather bf16 rows: lane l = row, wave w covers col-chunks 4w..4w+3
    uint4 v[4];
    if (l < nvalid) {
      const uint4* rowp = (const uint4*)(xb + (size_t)perm[slot0 + l] * DIM);
#pragma unroll
      for (int cc = 0; cc < 4; ++cc) v[cc] = rowp[w * 4 + cc];
    } else {
#pragma unroll
      for (int cc = 0; cc < 4; ++cc) { v[cc].x = 0u; v[cc].y = 0u; v[cc].z = 0u; v[cc].w = 0u; }
    }
#pragma unroll
    for (int cc = 0; cc < 4; ++cc)
      *(uint4*)(xa + (size_t)(w * 4 + cc) * 1024 + l * 16) = v[cc];
  } else {
    int r = t & 63;
    int half = t >> 6;
    unsigned pk[16];
    if (r < nvalid) {
      int token = perm[slot0 + r];
      const float* src = x + (size_t)token * DIM + half * 32;
#pragma unroll
      for (int q = 0; q < 8; ++q) {
        float4 vv = ((const float4*)src)[q];
        pk[q * 2 + 0] = (unsigned)f2bf(vv.x) | ((unsigned)f2bf(vv.y) << 16);
        pk[q * 2 + 1] = (unsigned)f2bf(vv.z) | ((unsigned)f2bf(vv.w) << 16);
      }
    } else {
#pragma unroll
      for (int q = 0; q < 16; ++q) pk[q] = 0u;
    }
#pragma unroll
    for (int cc = 0; cc < 4; ++cc) {
      uint4 u;
      u.x = pk[cc * 4 + 0]; u.y = pk[cc * 4 + 1]; u.z = pk[cc * 4 + 2]; u.w = pk[cc * 4 + 3];
      *(uint4*)(xa + (half * 4 + cc) * 1024 + r * 16) = u;
    }
  }

  const unsigned short* w1e = w1t + (size_t)e * DIM * HID;
  bf16x8 w1f[4][4];
#pragma unroll
  for (int kc = 0; kc < 4; ++kc)
#pragma unroll
    for (int jt = 0; jt < 4; ++jt)
      w1f[kc][jt] = *(const bf16x8*)(w1e + kc * 8192 + (w * 64 + jt * 16 + l15) * 32 + quad * 8);

  // gate value for the row this lane staged; broadcast later via shfl
  float gvl = (l < nvalid) ? gatev[slot0 + l] : 0.f;

  __syncthreads();

  f32x4 acc[4][4];
#pragma unroll
  for (int a = 0; a < 4; ++a)
#pragma unroll
    for (int b = 0; b < 4; ++b) {
      f32x4 z = {0.f, 0.f, 0.f, 0.f};
      acc[a][b] = z;
    }
#pragma unroll
  for (int kc = 0; kc < 4; ++kc) {
    bf16x8 af[4];
#pragma unroll
    for (int rt = 0; rt < 4; ++rt)
      af[rt] = *(const bf16x8*)(xa + (kc * 4 + quad) * 1024 + (rt * 16 + l15) * 16);
#pragma unroll
    for (int rt = 0; rt < 4; ++rt)
#pragma unroll
      for (int jt = 0; jt < 4; ++jt)
        acc[rt][jt] = __builtin_amdgcn_mfma_f32_16x16x32_bf16(af[rt], w1f[kc][jt], acc[rt][jt], 0, 0, 0);
  }

  const unsigned short* w2e = w2t + (size_t)e * HID * DIM;
  bf16x8 w2f[8][2];
#pragma unroll
  for (int hc = 0; hc < 8; ++hc)
#pragma unroll
    for (int jt = 0; jt < 2; ++jt)
      w2f[hc][jt] = *(const bf16x8*)(w2e + hc * 4096 + (w * 32 + jt * 16 + l15) * 32 + quad * 8);

  const float* b1e = b1 + e * HID;
#pragma unroll
  for (int jt = 0; jt < 4; ++jt) {
    int col = w * 64 + jt * 16 + l15;
    float b1v = b1e[col];
    int c = col >> 3;
    int byteoff = (col & 7) * 2;
#pragma unroll
    for (int rt = 0; rt < 4; ++rt) {
#pragma unroll
      for (int r = 0; r < 4; ++r) {
        int tokrow = rt * 16 + quad * 4 + r;
        float v = acc[rt][jt][r] + b1v;
        v = v > 0.f ? v : 0.f;
        *(unsigned short*)(ha + c * 1024 + tokrow * 16 + byteoff) = f2bf(v);
      }
    }
  }
  __syncthreads();

  f32x4 accc[4][2];
#pragma unroll
  for (int a = 0; a < 4; ++a)
#pragma unroll
    for (int b = 0; b < 2; ++b) {
      f32x4 z = {0.f, 0.f, 0.f, 0.f};
      accc[a][b] = z;
    }
#pragma unroll
  for (int hc = 0; hc < 8; ++hc) {
    bf16x8 ah[4];
#pragma unroll
    for (int rt = 0; rt < 4; ++rt)
      ah[rt] = *(const bf16x8*)(ha + (hc * 4 + quad) * 1024 + (rt * 16 + l15) * 16);
#pragma unroll
    for (int rt = 0; rt < 4; ++rt)
#pragma unroll
      for (int jt = 0; jt < 2; ++jt)
        accc[rt][jt] = __builtin_amdgcn_mfma_f32_16x16x32_bf16(ah[rt], w2f[hc][jt], accc[rt][jt], 0, 0, 0);
  }

  int dbase = w * 32;
  float b2v0 = b2[e * DIM + dbase + l15];
  float b2v1 = b2[e * DIM + dbase + 16 + l15];
#pragma unroll
  for (int rt = 0; rt < 4; ++rt) {
#pragma unroll
    for (int r = 0; r < 4; ++r) {
      int tokrow = rt * 16 + quad * 4 + r;
      float g = __shfl(gvl, tokrow);   // all lanes participate (tokrow in 0..63)
      if (tokrow < nvalid) {
        int pos = slot0 + tokrow;
        if (YB) {
          unsigned short* yrow = ybuf + (size_t)pos * DIM + dbase;
          yrow[l15] = f2bf(g * (accc[rt][0][r] + b2v0));
          yrow[16 + l15] = f2bf(g * (accc[rt][1][r] + b2v1));
        } else {
          int token = perm[pos];
          float* orow = out + (size_t)token * DIM + dbase;
          atomicAdd(&orow[l15], g * (accc[rt][0][r] + b2v0));
          atomicAdd(&orow[16 + l15], g * (accc[rt][1][r] + b2v1));
        }
      }
    }
  }
}

// ---------------- combine: out[n] = y[inv[2n]] + y[inv[2n+1]] ----------------
__global__ __launch_bounds__(256) void k_combine(const unsigned short* __restrict__ ybuf,
                                                 const int* __restrict__ inv,
                                                 float* __restrict__ out) {
  int t = threadIdx.x;
  int n = blockIdx.x * 16 + (t >> 4);
  int lane = t & 15;
  int p0 = inv[n * 2 + 0];
  int p1 = inv[n * 2 + 1];
  uint4 a = *((const uint4*)(ybuf + (size_t)p0 * DIM) + lane);
  uint4 b = *((const uint4*)(ybuf + (size_t)p1 * DIM) + lane);
  unsigned av[4] = {a.x, a.y, a.z, a.w}, bv[4] = {b.x, b.y, b.z, b.w};
  float r[8];
#pragma unroll
  for (int q = 0; q < 4; ++q) {
    r[q * 2 + 0] = bf2f(av[q] & 0xffffu) + bf2f(bv[q] & 0xffffu);
    r[q * 2 + 1] = bf2f(av[q] >> 16) + bf2f(bv[q] >> 16);
  }
  float* orow = out + (size_t)n * DIM + lane * 8;
  float4 w0 = {r[0], r[1], r[2], r[3]}, w1 = {r[4], r[5], r[6], r[7]};
  ((float4*)orow)[0] = w0;
  ((float4*)orow)[1] = w1;
}

extern "C" void kernel_launch(void* const* d_in, const int* in_sizes, int n_in,
                              void* d_out, int out_size, void* d_ws, size_t ws_size,
                              hipStream_t stream) {
  const float* x  = (const float*)d_in[0];
  const float* W1 = (const float*)d_in[1];
  const float* b1 = (const float*)d_in[2];
  const float* W2 = (const float*)d_in[3];
  const float* b2 = (const float*)d_in[4];
  const float* Wr = (const float*)d_in[5];
  const float* br = (const float*)d_in[6];
  float* out = (float*)d_out;

  char* ws = (char*)d_ws;
  float* importance   = (float*)(ws + 0);       // 32 f
  int*   counts       = (int*)(ws + 128);       // 32 i
  int*   cursors      = (int*)(ws + 256);       // 32 i
  int*   offsets      = (int*)(ws + 384);       // 33 i
  int*   top_idx      = (int*)(ws + 1024);              // 131072 i
  float* top_val      = (float*)(ws + 525312);          // 131072 f
  int*   perm         = (int*)(ws + 1049600);           // 133120 i
  float* gatev        = (float*)(ws + 1582080);         // 133120 f
  int*   inv          = (int*)(ws + 2114560);           // 131072 i -> 2638848
  unsigned short* w1t = (unsigned short*)(ws + 2638848);            // 2 MB -> 4736000
  unsigned short* w2t = (unsigned short*)(ws + 4736000);            // 2 MB -> 6833152
  unsigned short* ybuf = (unsigned short*)(ws + 6833152);           // 34078720 -> 40911872
  double* wrt64 = (double*)(ws + 6833152);            // 32 KB, aliases ybuf head (dead before k_expert)
  unsigned short* wrb = (unsigned short*)(ws + 6833152 + 32768);  // 32 KB, aliases ybuf (dead before k_expert)
  int* suspects = (int*)(ws + 40911872);              // 65536 i -> 41174016
  int* n_suspect = (int*)(ws + 41174016);             // -> 41174144
  const size_t NEEDED = 41174144;
  bool use_ybuf = ws_size >= NEEDED;

  // bf16 copy of x lives in the head of `out` (16.8 MB of its 33.5 MB): written
  // by k_router, read by k_expert<1>, dead before k_combine rewrites out.
  unsigned short* xb = (unsigned short*)out;

  hipLaunchKernelGGL(k_weights, dim3(513), dim3(256), 0, stream, W1, W2, Wr, w1t, w2t, wrt64,
                     wrb, (float*)ws, n_suspect);
  if (use_ybuf) {
    hipLaunchKernelGGL(k_router, dim3(512), dim3(256), 0, stream, x, wrb, br, top_idx, top_val,
                       xb, counts, importance, suspects, n_suspect);
    hipLaunchKernelGGL(k_router_fix, dim3(128), dim3(256), 0, stream, x, wrt64, br, suspects,
                       n_suspect, top_idx, top_val, counts, importance);
    hipLaunchKernelGGL(k_scatter, dim3(128), dim3(256), 0, stream, top_idx, top_val, counts,
                       importance, cursors, perm, gatev, inv, offsets,
                       out + (size_t)N_TOK * DIM);
    hipLaunchKernelGGL((k_expert<1>), dim3(2080), dim3(256), 0, stream, x, xb, w1t, w2t, b1, b2,
                       offsets, counts, perm, gatev, ybuf, out);
    hipLaunchKernelGGL(k_combine, dim3(4096), dim3(256), 0, stream, ybuf, inv, out);
  } else {
    hipLaunchKernelGGL(k_router_f64, dim3(8192), dim3(256), 0, stream, x, wrt64, br, top_idx,
                       top_val);
    hipLaunchKernelGGL(k_hist, dim3(256), dim3(256), 0, stream, top_idx, top_val, counts,
                       importance);
    hipLaunchKernelGGL(k_scatter, dim3(128), dim3(256), 0, stream, top_idx, top_val, counts,
                       importance, cursors, perm, gatev, inv, offsets,
                       out + (size_t)N_TOK * DIM);
    hipLaunchKernelGGL(k_zero_out, dim3(4096), dim3(256), 0, stream, out);
    hipLaunchKernelGGL((k_expert<0>), dim3(2080), dim3(256), 0, stream, x,
                       (const unsigned short*)0, w1t, w2t, b1, b2, offsets, counts, perm, gatev,
                       ybuf, out);
  }
}